// Round 7
// baseline (168.153 us; speedup 1.0000x reference)
//
#include <hip/hip_runtime.h>
#include <hip/hip_bf16.h>

// RGCN fused: per-relation aggregate (gather, fp32 acc) -> MFMA GEMM (K=8*64=512).
// x/linear fp32 on device, fp32 out (established r1-r3). Round 7:
//  - pack kernel converts x -> bf16 rows (128 B/row) in d_ws: halves gather
//    bytes AND halves HBM cost of L3 misses (r6: FETCH=135MB vs 46MB unique).
//  - THREADS 512->1024, wave owns 4 nodes, 2 blocks/CU -> 32 waves/CU TLP
//    (r6 post-mortem: gather is MLP-limited, ~3 loads in flight per CU).
//  - loads now dwordx2 (24 VGPR/batch) -> batch survives RA under (1024,2).
// W stays pre-packed as bf16 B-fragments in d_ws (L2-hot).

#define THREADS 1024
#define NPB 64            // nodes per block
#define KDIM 512          // NUM_REL * IN_CH
#define LDA 520           // padded bf16 row stride (1040 B)
#define MAXE 1024         // LDS edge-meta capacity (deg 12 -> 768 used)
#define WFRAG (4 * 16 * 64 * 8)   // 32768 bf16 B-fragment elements (64 KB)

typedef __attribute__((ext_vector_type(8))) short bf16x8;
typedef __attribute__((ext_vector_type(4))) float f32x4;

extern __shared__ __align__(16) char smem[];

__device__ __forceinline__ unsigned short f2bf(float f) {
  __hip_bfloat16 h = __float2bfloat16(f);
  return *reinterpret_cast<unsigned short*>(&h);
}

// ---- pack: W -> bf16 B-fragments (ws[0:64KB]); x -> bf16 rows (ws[64KB:]) ----
__global__ __launch_bounds__(256) void pack_wx(const void* __restrict__ wv,
                                               const void* __restrict__ xv,
                                               unsigned short* __restrict__ wsB,
                                               unsigned short* __restrict__ wsX,
                                               int nx) {   // nx = N*64 (0 if no x pack)
  const int lane = threadIdx.x & 63;
  const unsigned ww = ((const unsigned*)wv)[lane];
  const int exw = (int)((ww >> 7) & 0xFFu);
  const bool w_bf16 = __popcll(__ballot(exw >= 96 && exw < 160)) >= 48;
  const unsigned xw = ((const unsigned*)xv)[lane];
  const int exx = (int)((xw >> 7) & 0xFFu);
  const bool x_bf16 = __popcll(__ballot(exx >= 96 && exx < 160)) >= 48;

  const int total = WFRAG + nx;
  for (int i = blockIdx.x * 256 + threadIdx.x; i < total; i += gridDim.x * 256) {
    if (i < WFRAG) {
      const int j  = i & 7;
      const int l  = (i >> 3) & 63;
      const int kt = (i >> 9) & 15;
      const int nt = i >> 13;
      const int k  = kt * 32 + (l >> 4) * 8 + j;
      const int n  = nt * 16 + (l & 15);
      float v;
      if (w_bf16) v = __bfloat162float(((const __hip_bfloat16*)wv)[k * 64 + n]);
      else        v = ((const float*)wv)[k * 64 + n];
      wsB[i] = f2bf(v);
    } else {
      const int xi = i - WFRAG;
      if (x_bf16) wsX[xi] = ((const unsigned short*)xv)[xi];
      else        wsX[xi] = f2bf(((const float*)xv)[xi]);
    }
  }
}

#define ACC_SW(accrow, r, vv)                                        \
  switch (r) {                                                       \
    case 0: accrow[0] += (vv); break; case 1: accrow[1] += (vv); break; \
    case 2: accrow[2] += (vv); break; case 3: accrow[3] += (vv); break; \
    case 4: accrow[4] += (vv); break; case 5: accrow[5] += (vv); break; \
    case 6: accrow[6] += (vv); break; default: accrow[7] += (vv); break; }

__global__ __launch_bounds__(THREADS, 2)
void rgcn_fused(const void* __restrict__ xv,
                const void* __restrict__ wv,
                const int* __restrict__ p32,
                const int* __restrict__ i32,
                const int* __restrict__ t32,
                const unsigned short* __restrict__ wsB,  // null -> W in LDS
                const unsigned short* __restrict__ wsX,  // null -> gather global x
                float* __restrict__ out,
                int num_nodes) {
  __hip_bfloat16* aggS = (__hip_bfloat16*)smem;                 // [NPB][LDA]
  __hip_bfloat16* wtS  = aggS + NPB * LDA;                      // only if !wsB
  char* tail = smem + (size_t)NPB * LDA * 2 + (wsB ? 0 : (size_t)64 * LDA * 2);
  float*    invS  = (float*)tail;                               // [64]
  int*      ptrS  = (int*)(tail + 256);                         // [65]
  unsigned* eMeta = (unsigned*)(tail + 256 + 272);              // [MAXE]

  const int tid   = threadIdx.x;
  const int lane  = tid & 63;
  const int wvid  = tid >> 6;              // 0..15
  const int node0 = blockIdx.x * NPB;

  // runtime dtype / index-width detection (block-uniform)
  const unsigned xword = ((const unsigned*)xv)[lane];
  const int exf = (int)((xword >> 7) & 0xFFu);
  const bool x_bf16 = __popcll(__ballot(exf >= 96 && exf < 160)) >= 48;
  const bool idx64 = (p32[1] == 0);

  auto ldptr = [&](int n) -> int { return idx64 ? p32[2 * n] : p32[n]; };

  const int ntop   = min(node0 + NPB, num_nodes);
  const int e_lo   = ldptr(node0);
  const int ecount = ldptr(ntop) - e_lo;
  const bool staged = (ecount > 0 && ecount <= MAXE);

  for (int i = tid; i <= NPB; i += THREADS)
    ptrS[i] = ldptr(min(node0 + i, num_nodes));

  if (staged) {
    for (int e = tid; e < ecount; e += THREADS) {
      const int ge = e_lo + e;
      const unsigned s = (unsigned)(idx64 ? i32[2 * ge] : i32[ge]);
      const unsigned r = (unsigned)(idx64 ? t32[2 * ge] : t32[ge]);
      eMeta[e] = s | (r << 24);
    }
  }

  if (!wsB) {  // fallback: stage W^T in LDS
    if (x_bf16) {
      const __hip_bfloat16* wb = (const __hip_bfloat16*)wv;
      for (int i = tid; i < KDIM * 64; i += THREADS)
        wtS[(i & 63) * LDA + (i >> 6)] = wb[i];
    } else {
      const float* wf = (const float*)wv;
      for (int i = tid; i < KDIM * 64; i += THREADS)
        wtS[(i & 63) * LDA + (i >> 6)] = __float2bfloat16(wf[i]);
    }
  }

  __syncthreads();

  // inverse degree
  for (int i = tid; i < NPB; i += THREADS) {
    const int d = ptrS[i + 1] - ptrS[i];
    invS[i] = (d > 0 && node0 + i < num_nodes) ? 1.0f / (float)d : 0.0f;
  }

  // sort each deg-12 node's metas by relation (top byte); thread = node
  if (staged && tid < NPB) {
    const int e0 = ptrS[tid] - e_lo;
    if (ptrS[tid + 1] - ptrS[tid] == 12) {
      unsigned a[12];
#pragma unroll
      for (int j = 0; j < 12; ++j) a[j] = eMeta[e0 + j];
#pragma unroll
      for (int r = 0; r < 12; ++r)
#pragma unroll
        for (int i = (r & 1); i + 1 < 12; i += 2) {
          const unsigned lo = min(a[i], a[i + 1]);
          const unsigned hi = max(a[i], a[i + 1]);
          a[i] = lo; a[i + 1] = hi;
        }
#pragma unroll
      for (int j = 0; j < 12; ++j) eMeta[e0 + j] = a[j];
    }
  }

  __syncthreads();

  const int c16 = lane & 15;
  const int qd  = lane >> 4;

  // ---- gather: wave owns 4 nodes; quad qd owns node wvid*4+qd ----
  auto gather = [&](auto loadrow) {
    const int nlb = wvid * 4;
    const int eq0 = ptrS[nlb + qd] - e_lo;
    const int dq  = ptrS[nlb + qd + 1] - e_lo - eq0;
    const bool okfast = staged && (node0 + nlb + 3 < num_nodes) &&
                        (__ballot(dq == 12) == ~0ull);
    if (okfast) {
      unsigned m[12];
#pragma unroll
      for (int j = 0; j < 12; ++j) m[j] = eMeta[eq0 + j];
      float4 v[12];
#pragma unroll
      for (int j = 0; j < 12; ++j)
        v[j] = loadrow((int)(m[j] & 0x00FFFFFFu), c16);
      __builtin_amdgcn_sched_barrier(0);

      unsigned short* dst0 =
          (unsigned short*)(aggS + (nlb + qd) * LDA) + 4 * c16;
      const ushort4 z4 = {0, 0, 0, 0};
#pragma unroll
      for (int r = 0; r < 8; ++r) *(ushort4*)(dst0 + r * 64) = z4;

      // sorted-run accumulate with overwrite-flush (same-lane DS ops ordered)
      float4 cur = make_float4(0.f, 0.f, 0.f, 0.f);
      unsigned prev = 0xFFFFFFFFu;
#pragma unroll
      for (int j = 0; j < 12; ++j) {
        const unsigned rj = m[j] >> 24;
        const float mk = (rj == prev) ? 1.0f : 0.0f;
        cur.x = fmaf(cur.x, mk, v[j].x);
        cur.y = fmaf(cur.y, mk, v[j].y);
        cur.z = fmaf(cur.z, mk, v[j].z);
        cur.w = fmaf(cur.w, mk, v[j].w);
        ushort4 b;
        b.x = f2bf(cur.x); b.y = f2bf(cur.y);
        b.z = f2bf(cur.z); b.w = f2bf(cur.w);
        *(ushort4*)(dst0 + rj * 64) = b;
        prev = rj;
      }
    } else {
      // generic: full wave per node, lane = channel, wave-uniform switch
#pragma unroll
      for (int t = 0; t < 4; ++t) {
        const int nl = nlb + t;
        float a[8] = {0.f, 0.f, 0.f, 0.f, 0.f, 0.f, 0.f, 0.f};
        if (node0 + nl < num_nodes) {
          const int e0 = ptrS[nl] - e_lo, e1 = ptrS[nl + 1] - e_lo;
          for (int e = e0; e < e1; ++e) {
            unsigned mm;
            if (staged) mm = eMeta[e];
            else {
              const int ge = e_lo + e;
              mm = (unsigned)(idx64 ? i32[2 * ge] : i32[ge]) |
                   ((unsigned)(idx64 ? t32[2 * ge] : t32[ge]) << 24);
            }
            const size_t off = (size_t)(mm & 0x00FFFFFFu) * 64 + lane;
            const float vv = x_bf16
                ? __bfloat162float(((const __hip_bfloat16*)xv)[off])
                : ((const float*)xv)[off];
            const int r = __builtin_amdgcn_readfirstlane((int)(mm >> 24));
            ACC_SW(a, r, vv)
          }
        }
#pragma unroll
        for (int r = 0; r < 8; ++r)
          aggS[nl * LDA + r * 64 + lane] = __float2bfloat16(a[r]);
      }
    }
  };

  if (wsX) {
    // bf16 rows in ws: 128 B/row, dwordx2 per lane (4 channels)
    auto lr = [&](int src, int c) -> float4 {
      const uint2 u = ((const uint2*)wsX)[src * 16 + c];
      float4 f;
      f.x = __uint_as_float(u.x << 16);
      f.y = __uint_as_float(u.x & 0xFFFF0000u);
      f.z = __uint_as_float(u.y << 16);
      f.w = __uint_as_float(u.y & 0xFFFF0000u);
      return f;
    };
    gather(lr);
  } else if (x_bf16) {
    auto lr = [&](int src, int c) -> float4 {
      const ushort4 u = ((const ushort4*)xv)[src * 16 + c];
      float4 f;
      f.x = __uint_as_float((unsigned)(unsigned short)u.x << 16);
      f.y = __uint_as_float((unsigned)(unsigned short)u.y << 16);
      f.z = __uint_as_float((unsigned)(unsigned short)u.z << 16);
      f.w = __uint_as_float((unsigned)(unsigned short)u.w << 16);
      return f;
    };
    gather(lr);
  } else {
    auto lr = [&](int src, int c) -> float4 {
      return ((const float4*)xv)[src * 16 + c];
    };
    gather(lr);
  }

  __syncthreads();

  // ---- MFMA: 16 waves, one 16x16 tile each; out[64x64] = agg @ Wcat ----
  const int mt = wvid >> 2;
  const int nt = wvid & 3;
  const int mi = lane & 15;
  const int q4 = lane >> 4;
  const __hip_bfloat16* ap = aggS + (mt * 16 + mi) * LDA + q4 * 8;
  f32x4 c0 = {0.f, 0.f, 0.f, 0.f};
  if (wsB) {
    const bf16x8* B = (const bf16x8*)wsB;
#pragma unroll
    for (int kt = 0; kt < KDIM / 32; ++kt) {
      const bf16x8 a = *(const bf16x8*)(ap + kt * 32);
      const bf16x8 b = B[(nt * 16 + kt) * 64 + lane];
      c0 = __builtin_amdgcn_mfma_f32_16x16x32_bf16(a, b, c0, 0, 0, 0);
    }
  } else {
    const __hip_bfloat16* bp = wtS + (nt * 16 + mi) * LDA + q4 * 8;
#pragma unroll
    for (int kt = 0; kt < KDIM / 32; ++kt) {
      const bf16x8 a = *(const bf16x8*)(ap + kt * 32);
      const bf16x8 b = *(const bf16x8*)(bp + kt * 32);
      c0 = __builtin_amdgcn_mfma_f32_16x16x32_bf16(a, b, c0, 0, 0, 0);
    }
  }

  // D layout: col = lane&15, row = q4*4 + reg -> fp32 stores
#pragma unroll
  for (int i = 0; i < 4; ++i) {
    const int nl   = mt * 16 + q4 * 4 + i;
    const int node = node0 + nl;
    if (node < num_nodes)
      out[(size_t)node * 64 + nt * 16 + mi] = c0[i] * invS[nl];
  }
}

extern "C" void kernel_launch(void* const* d_in, const int* in_sizes, int n_in,
                              void* d_out, int out_size, void* d_ws, size_t ws_size,
                              hipStream_t stream) {
  const void* x   = d_in[0];
  const void* w   = d_in[1];
  const int*  ptr = (const int*)d_in[2];
  const int*  idx = (const int*)d_in[3];
  const int*  et  = (const int*)d_in[4];
  float*      out = (float*)d_out;

  const int num_nodes = in_sizes[0] / 64;   // x is [N, 64]
  const int nx = num_nodes * 64;

  const size_t needB = (size_t)WFRAG * 2;
  const size_t needX = needB + (size_t)nx * 2;
  const bool haveB = (d_ws != nullptr) && (ws_size >= needB);
  const bool haveX = (d_ws != nullptr) && (ws_size >= needX);
  unsigned short* wsB = haveB ? (unsigned short*)d_ws : nullptr;
  unsigned short* wsX = haveX ? (unsigned short*)d_ws + WFRAG : nullptr;

  if (haveB)
    pack_wx<<<256, 256, 0, stream>>>(w, x, wsB, wsX, haveX ? nx : 0);

  const size_t lds_bytes = (size_t)NPB * LDA * 2 +
                           (haveB ? 0 : (size_t)64 * LDA * 2) +
                           256 + 272 + (size_t)MAXE * 4;

  hipFuncSetAttribute((const void*)rgcn_fused,
                      hipFuncAttributeMaxDynamicSharedMemorySize,
                      (int)lds_bytes);

  const int nblocks = (num_nodes + NPB - 1) / NPB;
  rgcn_fused<<<nblocks, THREADS, lds_bytes, stream>>>(x, w, ptr, idx, et, wsB,
                                                      wsX, out, num_nodes);
}

// Round 8
// 139.504 us; speedup vs baseline: 1.2054x; 1.2054x over previous
//
#include <hip/hip_runtime.h>
#include <hip/hip_bf16.h>

// RGCN fused: per-relation aggregate (gather, fp32 acc) -> MFMA GEMM (K=8*64=512).
// x/linear fp32 on device, fp32 out (established r1-r3). Round 8:
//  - NPB 64->32, 512 thr: LDS 35.9 KB -> 4 blocks/CU = 32 waves/CU TLP
//    (r6/r7 showed gather is MLP-limited; per-wave ILP keeps losing to RA).
//  - __launch_bounds__(512,8) caps VGPR at 64 -> all 32 waves resident.
//  - gather: 2 batches of 6 raw float4 loads (24 VGPR), sorted-run accumulate.
//  - x-pack dropped (r7: pack cost 29.6 us > 3.5 us kernel gain). W pack kept,
//    full-grid 1-elem/thread (~2 us).

#define THREADS 512
#define NPB 32            // nodes per block (100000 = 32*3125, exact)
#define KDIM 512          // NUM_REL * IN_CH
#define LDA 520           // padded bf16 row stride (1040 B)
#define MAXE 512          // LDS edge-meta capacity (deg 12 -> 384 used)
#define WFRAG (4 * 16 * 64 * 8)   // 32768 bf16 B-fragment elements (64 KB)

typedef __attribute__((ext_vector_type(8))) short bf16x8;
typedef __attribute__((ext_vector_type(4))) float f32x4;

extern __shared__ __align__(16) char smem[];

__device__ __forceinline__ unsigned short f2bf(float f) {
  __hip_bfloat16 h = __float2bfloat16(f);
  return *reinterpret_cast<unsigned short*>(&h);
}

// ---- pack W (fp32 or bf16, [512][64]) -> bf16 B-fragment order in ws ----
__global__ __launch_bounds__(256) void pack_w(const void* __restrict__ wv,
                                              unsigned short* __restrict__ wsB) {
  const int lane = threadIdx.x & 63;
  const unsigned word = ((const unsigned*)wv)[lane];
  const int exf = (int)((word >> 7) & 0xFFu);
  const bool w_bf16 = __popcll(__ballot(exf >= 96 && exf < 160)) >= 48;
  const int i = blockIdx.x * 256 + threadIdx.x;   // grid covers WFRAG exactly
  if (i < WFRAG) {
    const int j  = i & 7;
    const int l  = (i >> 3) & 63;
    const int kt = (i >> 9) & 15;
    const int nt = i >> 13;
    const int k  = kt * 32 + (l >> 4) * 8 + j;
    const int n  = nt * 16 + (l & 15);
    float v;
    if (w_bf16) v = __bfloat162float(((const __hip_bfloat16*)wv)[k * 64 + n]);
    else        v = ((const float*)wv)[k * 64 + n];
    wsB[i] = f2bf(v);
  }
}

#define ACC_SW(accrow, r, vv)                                        \
  switch (r) {                                                       \
    case 0: accrow[0] += (vv); break; case 1: accrow[1] += (vv); break; \
    case 2: accrow[2] += (vv); break; case 3: accrow[3] += (vv); break; \
    case 4: accrow[4] += (vv); break; case 5: accrow[5] += (vv); break; \
    case 6: accrow[6] += (vv); break; default: accrow[7] += (vv); break; }

__global__ __launch_bounds__(THREADS, 8)   // 8 waves/EU -> VGPR<=64 -> 4 blk/CU
void rgcn_fused(const void* __restrict__ xv,
                const void* __restrict__ wv,
                const int* __restrict__ p32,
                const int* __restrict__ i32,
                const int* __restrict__ t32,
                const unsigned short* __restrict__ wsB,  // null -> W in LDS
                float* __restrict__ out,
                int num_nodes) {
  __hip_bfloat16* aggS = (__hip_bfloat16*)smem;                 // [NPB][LDA]
  __hip_bfloat16* wtS  = aggS + NPB * LDA;                      // only if !wsB
  char* tail = smem + (size_t)NPB * LDA * 2 + (wsB ? 0 : (size_t)64 * LDA * 2);
  float*    invS  = (float*)tail;                               // [NPB]
  int*      ptrS  = (int*)(tail + 256);                         // [NPB+1]
  unsigned* eMeta = (unsigned*)(tail + 256 + 272);              // [MAXE]

  const int tid   = threadIdx.x;
  const int lane  = tid & 63;
  const int wvid  = tid >> 6;              // 0..7
  const int node0 = blockIdx.x * NPB;

  // runtime dtype / index-width detection (block-uniform)
  const unsigned xword = ((const unsigned*)xv)[lane];
  const int exf = (int)((xword >> 7) & 0xFFu);
  const bool x_bf16 = __popcll(__ballot(exf >= 96 && exf < 160)) >= 48;
  const bool idx64 = (p32[1] == 0);

  auto ldptr = [&](int n) -> int { return idx64 ? p32[2 * n] : p32[n]; };

  const int ntop   = min(node0 + NPB, num_nodes);
  const int e_lo   = ldptr(node0);
  const int ecount = ldptr(ntop) - e_lo;
  const bool staged = (ecount > 0 && ecount <= MAXE);

  for (int i = tid; i <= NPB; i += THREADS)
    ptrS[i] = ldptr(min(node0 + i, num_nodes));

  if (staged) {
    for (int e = tid; e < ecount; e += THREADS) {
      const int ge = e_lo + e;
      const unsigned s = (unsigned)(idx64 ? i32[2 * ge] : i32[ge]);
      const unsigned r = (unsigned)(idx64 ? t32[2 * ge] : t32[ge]);
      eMeta[e] = s | (r << 24);
    }
  }

  if (!wsB) {  // fallback: stage W^T in LDS (1 blk/CU; only if ws too small)
    if (x_bf16) {
      const __hip_bfloat16* wb = (const __hip_bfloat16*)wv;
      for (int i = tid; i < KDIM * 64; i += THREADS)
        wtS[(i & 63) * LDA + (i >> 6)] = wb[i];
    } else {
      const float* wf = (const float*)wv;
      for (int i = tid; i < KDIM * 64; i += THREADS)
        wtS[(i & 63) * LDA + (i >> 6)] = __float2bfloat16(wf[i]);
    }
  }

  __syncthreads();

  // inverse degree
  for (int i = tid; i < NPB; i += THREADS) {
    const int d = ptrS[i + 1] - ptrS[i];
    invS[i] = (d > 0 && node0 + i < num_nodes) ? 1.0f / (float)d : 0.0f;
  }

  // sort each deg-12 node's metas by relation (top byte); thread = node
  if (staged && tid < NPB) {
    const int e0 = ptrS[tid] - e_lo;
    if (ptrS[tid + 1] - ptrS[tid] == 12) {
      unsigned a[12];
#pragma unroll
      for (int j = 0; j < 12; ++j) a[j] = eMeta[e0 + j];
#pragma unroll
      for (int r = 0; r < 12; ++r)
#pragma unroll
        for (int i = (r & 1); i + 1 < 12; i += 2) {
          const unsigned lo = min(a[i], a[i + 1]);
          const unsigned hi = max(a[i], a[i + 1]);
          a[i] = lo; a[i + 1] = hi;
        }
#pragma unroll
      for (int j = 0; j < 12; ++j) eMeta[e0 + j] = a[j];
    }
  }

  __syncthreads();

  const int c16 = lane & 15;
  const int qd  = lane >> 4;

  // ---- gather: wave owns 4 nodes; quad qd owns node wvid*4+qd ----
  auto gather = [&](auto loadrow) {
    const int nlb = wvid * 4;
    const int eq0 = ptrS[nlb + qd] - e_lo;
    const int dq  = ptrS[nlb + qd + 1] - e_lo - eq0;
    const bool okfast = staged && (node0 + nlb + 3 < num_nodes) &&
                        (__ballot(dq == 12) == ~0ull);
    if (okfast) {
      unsigned m[12];
#pragma unroll
      for (int j = 0; j < 12; ++j) m[j] = eMeta[eq0 + j];

      unsigned short* dst0 =
          (unsigned short*)(aggS + (nlb + qd) * LDA) + 4 * c16;
      const ushort4 z4 = {0, 0, 0, 0};
#pragma unroll
      for (int r = 0; r < 8; ++r) *(ushort4*)(dst0 + r * 64) = z4;

      float4 cur = make_float4(0.f, 0.f, 0.f, 0.f);
      unsigned prev = 0xFFFFFFFFu;
#pragma unroll
      for (int b = 0; b < 2; ++b) {
        // batch of 6 independent loads (24 VGPR) — fits the 64-VGPR cap
        float4 v[6];
#pragma unroll
        for (int j = 0; j < 6; ++j)
          v[j] = loadrow((int)(m[b * 6 + j] & 0x00FFFFFFu), c16);
        __builtin_amdgcn_sched_barrier(0);
        // sorted-run accumulate with overwrite-flush (same-lane DS ordered)
#pragma unroll
        for (int j = 0; j < 6; ++j) {
          const unsigned rj = m[b * 6 + j] >> 24;
          const float mk = (rj == prev) ? 1.0f : 0.0f;
          cur.x = fmaf(cur.x, mk, v[j].x);
          cur.y = fmaf(cur.y, mk, v[j].y);
          cur.z = fmaf(cur.z, mk, v[j].z);
          cur.w = fmaf(cur.w, mk, v[j].w);
          ushort4 bb;
          bb.x = f2bf(cur.x); bb.y = f2bf(cur.y);
          bb.z = f2bf(cur.z); bb.w = f2bf(cur.w);
          *(ushort4*)(dst0 + rj * 64) = bb;
          prev = rj;
        }
      }
    } else {
      // generic: full wave per node, lane = channel, wave-uniform switch
#pragma unroll
      for (int t = 0; t < 4; ++t) {
        const int nl = nlb + t;
        float a[8] = {0.f, 0.f, 0.f, 0.f, 0.f, 0.f, 0.f, 0.f};
        if (node0 + nl < num_nodes) {
          const int e0 = ptrS[nl] - e_lo, e1 = ptrS[nl + 1] - e_lo;
          for (int e = e0; e < e1; ++e) {
            unsigned mm;
            if (staged) mm = eMeta[e];
            else {
              const int ge = e_lo + e;
              mm = (unsigned)(idx64 ? i32[2 * ge] : i32[ge]) |
                   ((unsigned)(idx64 ? t32[2 * ge] : t32[ge]) << 24);
            }
            const size_t off = (size_t)(mm & 0x00FFFFFFu) * 64 + lane;
            const float vv = x_bf16
                ? __bfloat162float(((const __hip_bfloat16*)xv)[off])
                : ((const float*)xv)[off];
            const int r = __builtin_amdgcn_readfirstlane((int)(mm >> 24));
            ACC_SW(a, r, vv)
          }
        }
#pragma unroll
        for (int r = 0; r < 8; ++r)
          aggS[nl * LDA + r * 64 + lane] = __float2bfloat16(a[r]);
      }
    }
  };

  if (x_bf16) {
    auto lr = [&](int src, int c) -> float4 {
      const ushort4 u = ((const ushort4*)xv)[src * 16 + c];
      float4 f;
      f.x = __uint_as_float((unsigned)(unsigned short)u.x << 16);
      f.y = __uint_as_float((unsigned)(unsigned short)u.y << 16);
      f.z = __uint_as_float((unsigned)(unsigned short)u.z << 16);
      f.w = __uint_as_float((unsigned)(unsigned short)u.w << 16);
      return f;
    };
    gather(lr);
  } else {
    auto lr = [&](int src, int c) -> float4 {
      return ((const float4*)xv)[src * 16 + c];
    };
    gather(lr);
  }

  __syncthreads();

  // ---- MFMA: 8 waves, one 16x16 tile each; out[32x64] = agg @ Wcat ----
  const int mt = wvid >> 2;        // 0..1
  const int nt = wvid & 3;         // 0..3
  const int mi = lane & 15;
  const int q4 = lane >> 4;
  const __hip_bfloat16* ap = aggS + (mt * 16 + mi) * LDA + q4 * 8;
  f32x4 c0 = {0.f, 0.f, 0.f, 0.f};
  if (wsB) {
    const bf16x8* B = (const bf16x8*)wsB;
#pragma unroll
    for (int kt = 0; kt < KDIM / 32; ++kt) {
      const bf16x8 a = *(const bf16x8*)(ap + kt * 32);
      const bf16x8 b = B[(nt * 16 + kt) * 64 + lane];
      c0 = __builtin_amdgcn_mfma_f32_16x16x32_bf16(a, b, c0, 0, 0, 0);
    }
  } else {
    const __hip_bfloat16* bp = wtS + (nt * 16 + mi) * LDA + q4 * 8;
#pragma unroll
    for (int kt = 0; kt < KDIM / 32; ++kt) {
      const bf16x8 a = *(const bf16x8*)(ap + kt * 32);
      const bf16x8 b = *(const bf16x8*)(bp + kt * 32);
      c0 = __builtin_amdgcn_mfma_f32_16x16x32_bf16(a, b, c0, 0, 0, 0);
    }
  }

  // D layout: col = lane&15, row = q4*4 + reg -> fp32 stores
#pragma unroll
  for (int i = 0; i < 4; ++i) {
    const int nl   = mt * 16 + q4 * 4 + i;
    const int node = node0 + nl;
    if (node < num_nodes)
      out[(size_t)node * 64 + nt * 16 + mi] = c0[i] * invS[nl];
  }
}

extern "C" void kernel_launch(void* const* d_in, const int* in_sizes, int n_in,
                              void* d_out, int out_size, void* d_ws, size_t ws_size,
                              hipStream_t stream) {
  const void* x   = d_in[0];
  const void* w   = d_in[1];
  const int*  ptr = (const int*)d_in[2];
  const int*  idx = (const int*)d_in[3];
  const int*  et  = (const int*)d_in[4];
  float*      out = (float*)d_out;

  const int num_nodes = in_sizes[0] / 64;   // x is [N, 64]

  const bool haveB = (d_ws != nullptr) &&
                     (ws_size >= (size_t)WFRAG * sizeof(unsigned short));
  unsigned short* wsB = haveB ? (unsigned short*)d_ws : nullptr;
  if (haveB) pack_w<<<WFRAG / 256, 256, 0, stream>>>(w, wsB);

  const size_t lds_bytes = (size_t)NPB * LDA * 2 +
                           (haveB ? 0 : (size_t)64 * LDA * 2) +
                           256 + 272 + (size_t)MAXE * 4;

  hipFuncSetAttribute((const void*)rgcn_fused,
                      hipFuncAttributeMaxDynamicSharedMemorySize,
                      (int)lds_bytes);

  const int nblocks = (num_nodes + NPB - 1) / NPB;
  rgcn_fused<<<nblocks, THREADS, lds_bytes, stream>>>(x, w, ptr, idx, et, wsB,
                                                      out, num_nodes);
}

// Round 9
// 137.826 us; speedup vs baseline: 1.2200x; 1.0122x over previous
//
#include <hip/hip_runtime.h>
#include <hip/hip_bf16.h>

// RGCN fused: per-relation aggregate (gather, fp32 acc) -> MFMA GEMM (K=8*64=512).
// x/linear fp32 on device, fp32 out (established r1-r3). Round 9:
// r6/r7/r8 row-rate invariance => gather is capped by outstanding L2-miss
// lines per CU, so time ~ miss lines. Cut lines 2x: gather bf16 rows (128 B)
// from d_ws, packed by a properly vectorized pack_x (float4x2 -> ushort8,
// ~8 us; r7's naive pack was 29.6 us and masked the win).
// Fused kernel keeps r8's structure: NPB=32, 4 blocks/CU (35.9 KB LDS),
// (512,8) => VGPR<=64, 12 raw uint2 loads per quad in one batch (24 VGPR),
// conversion deferred to accumulate (avoids r7's convert-interleave waits).

#define THREADS 512
#define NPB 32            // nodes per block (100000 = 32*3125, exact)
#define KDIM 512          // NUM_REL * IN_CH
#define LDA 520           // padded bf16 row stride (1040 B)
#define MAXE 512          // LDS edge-meta capacity (deg 12 -> 384 used)
#define WFRAG (4 * 16 * 64 * 8)   // 32768 bf16 B-fragment elements (64 KB)

typedef __attribute__((ext_vector_type(8))) short bf16x8;
typedef __attribute__((ext_vector_type(4))) float f32x4;

extern __shared__ __align__(16) char smem[];

__device__ __forceinline__ unsigned short f2bf(float f) {
  __hip_bfloat16 h = __float2bfloat16(f);
  return *reinterpret_cast<unsigned short*>(&h);
}

// ---- pack W (fp32 or bf16, [512][64]) -> bf16 B-fragment order in ws ----
__global__ __launch_bounds__(256) void pack_w(const void* __restrict__ wv,
                                              unsigned short* __restrict__ wsB) {
  const int lane = threadIdx.x & 63;
  const unsigned word = ((const unsigned*)wv)[lane];
  const int exf = (int)((word >> 7) & 0xFFu);
  const bool w_bf16 = __popcll(__ballot(exf >= 96 && exf < 160)) >= 48;
  const int i = blockIdx.x * 256 + threadIdx.x;   // grid covers WFRAG exactly
  if (i < WFRAG) {
    const int j  = i & 7;
    const int l  = (i >> 3) & 63;
    const int kt = (i >> 9) & 15;
    const int nt = i >> 13;
    const int k  = kt * 32 + (l >> 4) * 8 + j;
    const int n  = nt * 16 + (l & 15);
    float v;
    if (w_bf16) v = __bfloat162float(((const __hip_bfloat16*)wv)[k * 64 + n]);
    else        v = ((const float*)wv)[k * 64 + n];
    wsB[i] = f2bf(v);
  }
}

// ---- pack x -> bf16 rows in ws (vectorized: 8 elems/thread, coalesced) ----
__global__ __launch_bounds__(256) void pack_x(const void* __restrict__ xv,
                                              unsigned short* __restrict__ wsX,
                                              int nx) {
  const int lane = threadIdx.x & 63;
  const unsigned word = ((const unsigned*)xv)[lane];
  const int exf = (int)((word >> 7) & 0xFFu);
  const bool x_bf16 = __popcll(__ballot(exf >= 96 && exf < 160)) >= 48;
  const int base = (blockIdx.x * 256 + threadIdx.x) * 8;
  if (base + 8 <= nx) {
    if (x_bf16) {
      *(uint4*)(wsX + base) = *(const uint4*)((const unsigned short*)xv + base);
    } else {
      const float4 a = *(const float4*)((const float*)xv + base);
      const float4 b = *(const float4*)((const float*)xv + base + 4);
      ushort4 lo, hi;
      lo.x = f2bf(a.x); lo.y = f2bf(a.y); lo.z = f2bf(a.z); lo.w = f2bf(a.w);
      hi.x = f2bf(b.x); hi.y = f2bf(b.y); hi.z = f2bf(b.z); hi.w = f2bf(b.w);
      *(ushort4*)(wsX + base)     = lo;
      *(ushort4*)(wsX + base + 4) = hi;
    }
  } else if (base < nx) {
    for (int i = base; i < nx; ++i)
      wsX[i] = x_bf16 ? ((const unsigned short*)xv)[i]
                      : f2bf(((const float*)xv)[i]);
  }
}

#define ACC_SW(accrow, r, vv)                                        \
  switch (r) {                                                       \
    case 0: accrow[0] += (vv); break; case 1: accrow[1] += (vv); break; \
    case 2: accrow[2] += (vv); break; case 3: accrow[3] += (vv); break; \
    case 4: accrow[4] += (vv); break; case 5: accrow[5] += (vv); break; \
    case 6: accrow[6] += (vv); break; default: accrow[7] += (vv); break; }

__global__ __launch_bounds__(THREADS, 8)   // VGPR<=64 -> 4 blocks/CU
void rgcn_fused(const void* __restrict__ xv,
                const void* __restrict__ wv,
                const int* __restrict__ p32,
                const int* __restrict__ i32,
                const int* __restrict__ t32,
                const unsigned short* __restrict__ wsB,  // null -> W in LDS
                const unsigned short* __restrict__ wsX,  // null -> global x
                float* __restrict__ out,
                int num_nodes) {
  __hip_bfloat16* aggS = (__hip_bfloat16*)smem;                 // [NPB][LDA]
  __hip_bfloat16* wtS  = aggS + NPB * LDA;                      // only if !wsB
  char* tail = smem + (size_t)NPB * LDA * 2 + (wsB ? 0 : (size_t)64 * LDA * 2);
  float*    invS  = (float*)tail;                               // [NPB]
  int*      ptrS  = (int*)(tail + 256);                         // [NPB+1]
  unsigned* eMeta = (unsigned*)(tail + 256 + 272);              // [MAXE]

  const int tid   = threadIdx.x;
  const int lane  = tid & 63;
  const int wvid  = tid >> 6;              // 0..7
  const int node0 = blockIdx.x * NPB;

  // runtime dtype / index-width detection (block-uniform)
  const unsigned xword = ((const unsigned*)xv)[lane];
  const int exf = (int)((xword >> 7) & 0xFFu);
  const bool x_bf16 = __popcll(__ballot(exf >= 96 && exf < 160)) >= 48;
  const bool idx64 = (p32[1] == 0);

  auto ldptr = [&](int n) -> int { return idx64 ? p32[2 * n] : p32[n]; };

  const int ntop   = min(node0 + NPB, num_nodes);
  const int e_lo   = ldptr(node0);
  const int ecount = ldptr(ntop) - e_lo;
  const bool staged = (ecount > 0 && ecount <= MAXE);

  for (int i = tid; i <= NPB; i += THREADS)
    ptrS[i] = ldptr(min(node0 + i, num_nodes));

  if (staged) {
    for (int e = tid; e < ecount; e += THREADS) {
      const int ge = e_lo + e;
      const unsigned s = (unsigned)(idx64 ? i32[2 * ge] : i32[ge]);
      const unsigned r = (unsigned)(idx64 ? t32[2 * ge] : t32[ge]);
      eMeta[e] = s | (r << 24);
    }
  }

  if (!wsB) {  // fallback: stage W^T in LDS (only if ws too small)
    if (x_bf16) {
      const __hip_bfloat16* wb = (const __hip_bfloat16*)wv;
      for (int i = tid; i < KDIM * 64; i += THREADS)
        wtS[(i & 63) * LDA + (i >> 6)] = wb[i];
    } else {
      const float* wf = (const float*)wv;
      for (int i = tid; i < KDIM * 64; i += THREADS)
        wtS[(i & 63) * LDA + (i >> 6)] = __float2bfloat16(wf[i]);
    }
  }

  __syncthreads();

  // inverse degree
  for (int i = tid; i < NPB; i += THREADS) {
    const int d = ptrS[i + 1] - ptrS[i];
    invS[i] = (d > 0 && node0 + i < num_nodes) ? 1.0f / (float)d : 0.0f;
  }

  // sort each deg-12 node's metas by relation (top byte); thread = node
  if (staged && tid < NPB) {
    const int e0 = ptrS[tid] - e_lo;
    if (ptrS[tid + 1] - ptrS[tid] == 12) {
      unsigned a[12];
#pragma unroll
      for (int j = 0; j < 12; ++j) a[j] = eMeta[e0 + j];
#pragma unroll
      for (int r = 0; r < 12; ++r)
#pragma unroll
        for (int i = (r & 1); i + 1 < 12; i += 2) {
          const unsigned lo = min(a[i], a[i + 1]);
          const unsigned hi = max(a[i], a[i + 1]);
          a[i] = lo; a[i + 1] = hi;
        }
#pragma unroll
      for (int j = 0; j < 12; ++j) eMeta[e0 + j] = a[j];
    }
  }

  __syncthreads();

  const int c16 = lane & 15;
  const int qd  = lane >> 4;

  const int nlb = wvid * 4;
  const int eq0 = ptrS[nlb + qd] - e_lo;
  const int dq  = ptrS[nlb + qd + 1] - e_lo - eq0;
  const bool okfast = staged && (node0 + nlb + 3 < num_nodes) &&
                      (__ballot(dq == 12) == ~0ull);

  if (okfast && wsX) {
    // ---- fast path: bf16 rows from ws, 12 raw uint2 loads in one batch ----
    unsigned m[12];
#pragma unroll
    for (int j = 0; j < 12; ++j) m[j] = eMeta[eq0 + j];

    uint2 u[12];
#pragma unroll
    for (int j = 0; j < 12; ++j)
      u[j] = ((const uint2*)wsX)[(size_t)(m[j] & 0x00FFFFFFu) * 16 + c16];
    __builtin_amdgcn_sched_barrier(0);

    unsigned short* dst0 = (unsigned short*)(aggS + (nlb + qd) * LDA) + 4 * c16;
    const ushort4 z4 = {0, 0, 0, 0};
#pragma unroll
    for (int r = 0; r < 8; ++r) *(ushort4*)(dst0 + r * 64) = z4;

    // sorted-run accumulate with overwrite-flush (same-lane DS ops ordered)
    float4 cur = make_float4(0.f, 0.f, 0.f, 0.f);
    unsigned prev = 0xFFFFFFFFu;
#pragma unroll
    for (int j = 0; j < 12; ++j) {
      const unsigned rj = m[j] >> 24;
      const float mk = (rj == prev) ? 1.0f : 0.0f;
      const float vx = __uint_as_float(u[j].x << 16);
      const float vy = __uint_as_float(u[j].x & 0xFFFF0000u);
      const float vz = __uint_as_float(u[j].y << 16);
      const float vw = __uint_as_float(u[j].y & 0xFFFF0000u);
      cur.x = fmaf(cur.x, mk, vx);
      cur.y = fmaf(cur.y, mk, vy);
      cur.z = fmaf(cur.z, mk, vz);
      cur.w = fmaf(cur.w, mk, vw);
      ushort4 bb;
      bb.x = f2bf(cur.x); bb.y = f2bf(cur.y);
      bb.z = f2bf(cur.z); bb.w = f2bf(cur.w);
      *(ushort4*)(dst0 + rj * 64) = bb;
      prev = rj;
    }
  } else if (okfast) {
    // fast path, global x (fp32 or bf16), float4-equivalent loads
    unsigned m[12];
#pragma unroll
    for (int j = 0; j < 12; ++j) m[j] = eMeta[eq0 + j];
    float4 v[12];
    if (x_bf16) {
#pragma unroll
      for (int j = 0; j < 12; ++j) {
        const ushort4 us =
            ((const ushort4*)xv)[(size_t)(m[j] & 0x00FFFFFFu) * 16 + c16];
        v[j].x = __uint_as_float((unsigned)(unsigned short)us.x << 16);
        v[j].y = __uint_as_float((unsigned)(unsigned short)us.y << 16);
        v[j].z = __uint_as_float((unsigned)(unsigned short)us.z << 16);
        v[j].w = __uint_as_float((unsigned)(unsigned short)us.w << 16);
      }
    } else {
#pragma unroll
      for (int j = 0; j < 12; ++j)
        v[j] = ((const float4*)xv)[(size_t)(m[j] & 0x00FFFFFFu) * 16 + c16];
    }
    __builtin_amdgcn_sched_barrier(0);

    unsigned short* dst0 = (unsigned short*)(aggS + (nlb + qd) * LDA) + 4 * c16;
    const ushort4 z4 = {0, 0, 0, 0};
#pragma unroll
    for (int r = 0; r < 8; ++r) *(ushort4*)(dst0 + r * 64) = z4;

    float4 cur = make_float4(0.f, 0.f, 0.f, 0.f);
    unsigned prev = 0xFFFFFFFFu;
#pragma unroll
    for (int j = 0; j < 12; ++j) {
      const unsigned rj = m[j] >> 24;
      const float mk = (rj == prev) ? 1.0f : 0.0f;
      cur.x = fmaf(cur.x, mk, v[j].x);
      cur.y = fmaf(cur.y, mk, v[j].y);
      cur.z = fmaf(cur.z, mk, v[j].z);
      cur.w = fmaf(cur.w, mk, v[j].w);
      ushort4 bb;
      bb.x = f2bf(cur.x); bb.y = f2bf(cur.y);
      bb.z = f2bf(cur.z); bb.w = f2bf(cur.w);
      *(ushort4*)(dst0 + rj * 64) = bb;
      prev = rj;
    }
  } else {
    // generic: full wave per node, lane = channel, wave-uniform switch
#pragma unroll
    for (int t = 0; t < 4; ++t) {
      const int nl = nlb + t;
      float a[8] = {0.f, 0.f, 0.f, 0.f, 0.f, 0.f, 0.f, 0.f};
      if (node0 + nl < num_nodes) {
        const int e0 = ptrS[nl] - e_lo, e1 = ptrS[nl + 1] - e_lo;
        for (int e = e0; e < e1; ++e) {
          unsigned mm;
          if (staged) mm = eMeta[e];
          else {
            const int ge = e_lo + e;
            mm = (unsigned)(idx64 ? i32[2 * ge] : i32[ge]) |
                 ((unsigned)(idx64 ? t32[2 * ge] : t32[ge]) << 24);
          }
          const size_t off = (size_t)(mm & 0x00FFFFFFu) * 64 + lane;
          const float vv = x_bf16
              ? __bfloat162float(((const __hip_bfloat16*)xv)[off])
              : ((const float*)xv)[off];
          const int r = __builtin_amdgcn_readfirstlane((int)(mm >> 24));
          ACC_SW(a, r, vv)
        }
      }
#pragma unroll
      for (int r = 0; r < 8; ++r)
        aggS[nl * LDA + r * 64 + lane] = __float2bfloat16(a[r]);
    }
  }

  __syncthreads();

  // ---- MFMA: 8 waves, one 16x16 tile each; out[32x64] = agg @ Wcat ----
  const int mt = wvid >> 2;        // 0..1
  const int nt = wvid & 3;         // 0..3
  const int mi = lane & 15;
  const int q4 = lane >> 4;
  const __hip_bfloat16* ap = aggS + (mt * 16 + mi) * LDA + q4 * 8;
  f32x4 c0 = {0.f, 0.f, 0.f, 0.f};
  if (wsB) {
    const bf16x8* B = (const bf16x8*)wsB;
#pragma unroll
    for (int kt = 0; kt < KDIM / 32; ++kt) {
      const bf16x8 a = *(const bf16x8*)(ap + kt * 32);
      const bf16x8 b = B[(nt * 16 + kt) * 64 + lane];
      c0 = __builtin_amdgcn_mfma_f32_16x16x32_bf16(a, b, c0, 0, 0, 0);
    }
  } else {
    const __hip_bfloat16* bp = wtS + (nt * 16 + mi) * LDA + q4 * 8;
#pragma unroll
    for (int kt = 0; kt < KDIM / 32; ++kt) {
      const bf16x8 a = *(const bf16x8*)(ap + kt * 32);
      const bf16x8 b = *(const bf16x8*)(bp + kt * 32);
      c0 = __builtin_amdgcn_mfma_f32_16x16x32_bf16(a, b, c0, 0, 0, 0);
    }
  }

  // D layout: col = lane&15, row = q4*4 + reg -> fp32 stores
#pragma unroll
  for (int i = 0; i < 4; ++i) {
    const int nl   = mt * 16 + q4 * 4 + i;
    const int node = node0 + nl;
    if (node < num_nodes)
      out[(size_t)node * 64 + nt * 16 + mi] = c0[i] * invS[nl];
  }
}

extern "C" void kernel_launch(void* const* d_in, const int* in_sizes, int n_in,
                              void* d_out, int out_size, void* d_ws, size_t ws_size,
                              hipStream_t stream) {
  const void* x   = d_in[0];
  const void* w   = d_in[1];
  const int*  ptr = (const int*)d_in[2];
  const int*  idx = (const int*)d_in[3];
  const int*  et  = (const int*)d_in[4];
  float*      out = (float*)d_out;

  const int num_nodes = in_sizes[0] / 64;   // x is [N, 64]
  const int nx = num_nodes * 64;

  const size_t needB = (size_t)WFRAG * 2;
  const size_t needX = needB + (size_t)nx * 2;
  const bool haveB = (d_ws != nullptr) && (ws_size >= needB);
  const bool haveX = (d_ws != nullptr) && (ws_size >= needX);
  unsigned short* wsB = haveB ? (unsigned short*)d_ws : nullptr;
  unsigned short* wsX = haveX ? (unsigned short*)d_ws + WFRAG : nullptr;

  if (haveB) pack_w<<<WFRAG / 256, 256, 0, stream>>>(w, wsB);
  if (haveX) {
    const int nthreads = (nx + 7) / 8;
    pack_x<<<(nthreads + 255) / 256, 256, 0, stream>>>(x, wsX, nx);
  }

  const size_t lds_bytes = (size_t)NPB * LDA * 2 +
                           (haveB ? 0 : (size_t)64 * LDA * 2) +
                           256 + 272 + (size_t)MAXE * 4;

  hipFuncSetAttribute((const void*)rgcn_fused,
                      hipFuncAttributeMaxDynamicSharedMemorySize,
                      (int)lds_bytes);

  const int nblocks = (num_nodes + NPB - 1) / NPB;
  rgcn_fused<<<nblocks, THREADS, lds_bytes, stream>>>(x, w, ptr, idx, et, wsB,
                                                      wsX, out, num_nodes);
}